// Round 10
// baseline (620.354 us; speedup 1.0000x reference)
//
#include <hip/hip_runtime.h>
#include <hip/hip_bf16.h>

// Problem constants
#define BT 32768      // B*T = 64*512
#define TSTEPS 512
#define NBATCH 64
#define KDIM 512      // IN_DIM
#define NPAD 192      // P row stride
#define NW 192        // Wc cols

#define L2E 1.4426950408889634f
#define T2E 2.8853900817779268f

__device__ __forceinline__ float rl(float v, int lane) {
    return __int_as_float(__builtin_amdgcn_readlane(__float_as_int(v), lane));
}
__device__ __forceinline__ float bperm(int byteidx, float v) {
    return __int_as_float(__builtin_amdgcn_ds_bpermute(byteidx, __float_as_int(v)));
}
// unified activation: a * rcp(1 + exp2(s*x + sc)) + b
__device__ __forceinline__ float actf(float x, float s, float sc, float a, float b) {
    float e = exp2f(fmaf(s, x, sc));
    return fmaf(a, __builtin_amdgcn_rcpf(1.f + e), b);
}

// P column layout (scan-friendly):
//   z dot (gate g, neuron i) -> col 4*i+g   (cols 0..131; lane i reads float4 @ 4i)
//   L0 dot e -> col 132+e                   (cols 132..185; lane 4+e reads scalar)
//   cols 186..191 pad (zero)
__device__ __forceinline__ int permpos(int o) {
    if (o < 132) { int g = o / 33, i = o - g * 33; return 4 * i + g; }
    return o;
}

// ---------------------------------------------------------------------------
// Kernel 1: fold fc1 into the stacked scan-input projection (permuted cols).
// ---------------------------------------------------------------------------
__global__ __launch_bounds__(256) void fold_kernel(
    const float* __restrict__ fc1_w, const float* __restrict__ fc1_b,
    const float* __restrict__ lstm_wi, const float* __restrict__ lstm_bi,
    const float* __restrict__ ff1w0, const float* __restrict__ ff2w0,
    const float* __restrict__ taw0, const float* __restrict__ tbw0,
    const float* __restrict__ ff1b0, const float* __restrict__ ff2b0,
    const float* __restrict__ tab0, const float* __restrict__ tbb0,
    const float* __restrict__ mask0,
    float* __restrict__ Wc, float* __restrict__ bc)
{
    const int o = blockIdx.x;   // 0..191 logical column
    const int t = threadIdx.x;  // 0..255 = latent index l
    const int p = permpos(o);
    __shared__ float wrow[256];
    __shared__ float red[256];

    float wl = 0.f, b0 = 0.f;
    if (o < 132) { wl = lstm_wi[o * 256 + t]; b0 = lstm_bi[o]; }
    else if (o < 186) {
        const int e = o - 132, m = e / 18, i = e - m * 18;
        if (m == 0)      { wl = ff1w0[i * 274 + t] * mask0[i * 274 + t]; b0 = ff1b0[i]; }
        else if (m == 1) { wl = ff2w0[i * 274 + t] * mask0[i * 274 + t]; b0 = ff2b0[i]; }
        else             { wl = taw0[i * 274 + t] + tbw0[i * 274 + t];   b0 = tab0[i] + tbb0[i]; }
    }
    wrow[t] = wl;
    __syncthreads();

    float acc0 = 0.f, acc1 = 0.f;
    for (int l = 0; l < 256; l++) {
        float w = wrow[l];
        acc0 = fmaf(fc1_w[l * 512 + t], w, acc0);
        acc1 = fmaf(fc1_w[l * 512 + t + 256], w, acc1);
    }
    Wc[(size_t)t * NW + p] = acc0;
    Wc[(size_t)(t + 256) * NW + p] = acc1;

    red[t] = fc1_b[t] * wl;
    __syncthreads();
    for (int s = 128; s > 0; s >>= 1) {
        if (t < s) red[t] += red[t + s];
        __syncthreads();
    }
    if (t == 0) bc[p] = red[0] + b0;
}

// ---------------------------------------------------------------------------
// Kernel 2: P[m][n] = sum_k X[m][k]*Wc[k][n] + bc[n], fp32 LDS-tiled GEMM.
// M=32768, K=512, N=192. Tile 128x64x16, 128 threads, 8x8 acc/thread.
// Inner k: 64 FMAs per 4 ds_read_b128 (halved LDS:FMA ratio vs R9 — the
// kernel was LDS-issue-bound: 3 reads/32 FMA = 92 us of LDS pipe).
// Grid (256, 3): n-tiles of 64 divide N=192 exactly (no padding waste).
// ---------------------------------------------------------------------------
__global__ __launch_bounds__(128) void gemm_kernel(
    const float* __restrict__ X, const float* __restrict__ Wc,
    const float* __restrict__ bc, float* __restrict__ P)
{
    __shared__ float As[16][128];   // [k][m]
    __shared__ float Bs[16][64];    // [k][n]
    const int tid = threadIdx.x;    // 0..127
    const int m0 = blockIdx.x * 128;
    const int n0 = blockIdx.y * 64;
    // A loader: row m0+tid, all 16 k (4 float4 from one row)
    // B loader: bk = tid>>3 (0..15), bn = (tid&7)*8 (2 float4)
    const int bk = tid >> 3;
    const int bn = (tid & 7) << 3;
    // compute mapping: 8 rows x 8 cols per thread
    const int tm = (tid & 15) << 3;   // 0..120
    const int tn = (tid >> 4) << 3;   // 0..56

    float acc[8][8];
#pragma unroll
    for (int i = 0; i < 8; i++)
#pragma unroll
        for (int j = 0; j < 8; j++) acc[i][j] = 0.f;

    const float* xp = X + (size_t)(m0 + tid) * KDIM;
    const float* wp = Wc + (size_t)bk * NW + n0 + bn;

    for (int k0 = 0; k0 < KDIM; k0 += 16) {
        const float4 a0 = *(const float4*)(xp + k0);
        const float4 a1 = *(const float4*)(xp + k0 + 4);
        const float4 a2 = *(const float4*)(xp + k0 + 8);
        const float4 a3 = *(const float4*)(xp + k0 + 12);
        const float4 b0 = *(const float4*)(wp + (size_t)k0 * NW);
        const float4 b1 = *(const float4*)(wp + (size_t)k0 * NW + 4);
        __syncthreads();
        As[0][tid] = a0.x;  As[1][tid] = a0.y;  As[2][tid] = a0.z;  As[3][tid] = a0.w;
        As[4][tid] = a1.x;  As[5][tid] = a1.y;  As[6][tid] = a1.z;  As[7][tid] = a1.w;
        As[8][tid] = a2.x;  As[9][tid] = a2.y;  As[10][tid] = a2.z; As[11][tid] = a2.w;
        As[12][tid] = a3.x; As[13][tid] = a3.y; As[14][tid] = a3.z; As[15][tid] = a3.w;
        *(float4*)&Bs[bk][bn] = b0;
        *(float4*)&Bs[bk][bn + 4] = b1;
        __syncthreads();
#pragma unroll
        for (int k = 0; k < 16; k++) {
            const float4 xa = *(const float4*)&As[k][tm];
            const float4 xb = *(const float4*)&As[k][tm + 4];
            const float4 ba = *(const float4*)&Bs[k][tn];
            const float4 bb = *(const float4*)&Bs[k][tn + 4];
            const float xs[8] = {xa.x, xa.y, xa.z, xa.w, xb.x, xb.y, xb.z, xb.w};
            const float bs[8] = {ba.x, ba.y, ba.z, ba.w, bb.x, bb.y, bb.z, bb.w};
#pragma unroll
            for (int i = 0; i < 8; i++)
#pragma unroll
                for (int j = 0; j < 8; j++)
                    acc[i][j] = fmaf(xs[i], bs[j], acc[i][j]);
        }
    }

    {
        const float4 bias0 = *(const float4*)(bc + n0 + tn);
        const float4 bias1 = *(const float4*)(bc + n0 + tn + 4);
        const float bias[8] = {bias0.x, bias0.y, bias0.z, bias0.w,
                               bias1.x, bias1.y, bias1.z, bias1.w};
#pragma unroll
        for (int i = 0; i < 8; i++) {
            float4 r0, r1;
            r0.x = acc[i][0] + bias[0]; r0.y = acc[i][1] + bias[1];
            r0.z = acc[i][2] + bias[2]; r0.w = acc[i][3] + bias[3];
            r1.x = acc[i][4] + bias[4]; r1.y = acc[i][5] + bias[5];
            r1.z = acc[i][6] + bias[6]; r1.w = acc[i][7] + bias[7];
            float* pp = P + (size_t)(m0 + tm + i) * NPAD + n0 + tn;
            *(float4*)pp = r0;
            *(float4*)(pp + 4) = r1;
        }
    }
}

// ---------------------------------------------------------------------------
// Kernel 3: persistent scan, one wave per batch element.  (unchanged from R8)
// ---------------------------------------------------------------------------
__global__ __launch_bounds__(64)
__attribute__((amdgpu_waves_per_eu(1, 1)))
void scan_kernel(
    const float* __restrict__ P, const float* __restrict__ lstm_wh,
    const float* __restrict__ ff1w0, const float* __restrict__ ff2w0,
    const float* __restrict__ taw0, const float* __restrict__ tbw0,
    const float* __restrict__ ff1w1, const float* __restrict__ ff2w1,
    const float* __restrict__ taw1, const float* __restrict__ tbw1,
    const float* __restrict__ ff1b1, const float* __restrict__ ff2b1,
    const float* __restrict__ tab1, const float* __restrict__ tbb1,
    const float* __restrict__ ff1w2, const float* __restrict__ ff2w2,
    const float* __restrict__ taw2, const float* __restrict__ tbw2,
    const float* __restrict__ ff1b2, const float* __restrict__ ff2b2,
    const float* __restrict__ tab2, const float* __restrict__ tbb2,
    const float* __restrict__ mask1, const float* __restrict__ mask2,
    float* __restrict__ out)
{
    const int L = threadIdx.x;
    const int b = blockIdx.x;

    // packed gate weights: G4[k*33+i] = (w_ia, w_ig, w_fg, w_og) for neuron i, term k
    __shared__ float4 G4[33 * 33];
    for (int idx = L; idx < 33 * 33; idx += 64) {
        const int k = idx / 33, i = idx - k * 33;
        float4 g;
        g.x = lstm_wh[i * 33 + k];
        g.y = lstm_wh[(33 + i) * 33 + k];
        g.z = lstm_wh[(66 + i) * 33 + k];
        g.w = lstm_wh[(99 + i) * 33 + k];
        G4[idx] = g;
    }
    __syncthreads();

    const int iG = (L < 33) ? L : 32;   // gate neuron (lanes 33..63 duplicate 32)

    // ---- L0 weights: dot e=L-4 (clamped), m=e/18; ta+tb merged ----
    float w0[18];
    {
        int e = L - 4; e = (e < 0) ? 0 : ((e > 53) ? 53 : e);
        const int m = e / 18, i = e - m * 18;
        const float* pa = (m == 0) ? ff1w0 : (m == 1) ? ff2w0 : taw0;
#pragma unroll
        for (int k = 0; k < 18; k++) {
            float w = pa[i * 274 + 256 + k];
            if (m == 2) w += tbw0[i * 274 + 256 + k];
            w0[k] = w;
        }
    }
    // ---- L1 weights: dot d=m*12+i on lanes 0..35 ----
    float w1[30], bias1;
    {
        const int d = (L < 36) ? L : 35;
        const int m = d / 12, i = d - m * 12;
        const float* pa = (m == 0) ? ff1w1 : (m == 1) ? ff2w1 : taw1;
#pragma unroll
        for (int k = 0; k < 30; k++) {
            float w = pa[i * 30 + k];
            if (m == 2) w += tbw1[i * 30 + k];
            else w *= mask1[i * 30 + k];
            w1[k] = w;
        }
        bias1 = (m == 0) ? ff1b1[i] : (m == 1) ? ff2b1[i] : (tab1[i] + tbb1[i]);
    }
    // ---- L2 weights: dot d=m*3+i on lanes 0..8 ----
    float w2[15], bias2;
    {
        const int d = (L < 9) ? L : 8;
        const int m = d / 3, i = d - m * 3;
        const float* pa = (m == 0) ? ff1w2 : (m == 1) ? ff2w2 : taw2;
#pragma unroll
        for (int k = 0; k < 15; k++) {
            float w = pa[i * 15 + k];
            if (m == 2) w += tbw2[i * 15 + k];
            else w *= mask2[i * 15 + k];
            w2[k] = w;
        }
        bias2 = (m == 0) ? ff1b2[i] : (m == 1) ? ff2b2[i] : (tab2[i] + tbb2[i]);
    }

    // ---- per-lane activation constants (layers only) ----
    const float s0  = (L < 40) ? -T2E : -L2E;   // L0: lanes 4..39 tanh, 40..57 sig
    const float a0c = (L < 40) ? 2.f : 1.f;
    const float b0c = (L < 40) ? -1.f : 0.f;
    const float s1  = (L < 24) ? -T2E : -L2E;
    const float a1c = (L < 24) ? 2.f : 1.f;
    const float b1c = (L < 24) ? -1.f : 0.f;
    const float s2  = (L < 6) ? -T2E : -L2E;
    const float a2c = (L < 6) ? 2.f : 1.f;
    const float b2c = (L < 6) ? -1.f : 0.f;

    // ---- per-lane bpermute byte indices (layer combines) ----
    const int x0f1 = (4 * (4 + L)) & 255;
    const int x0f2 = (4 * (22 + L)) & 255;
    const int x0ti = (4 * (40 + L)) & 255;
    const int x1f1 = (4 * L) & 255;
    const int x1f2 = (4 * (12 + L)) & 255;
    const int x1ti = (4 * (24 + L)) & 255;
    const int x2f1 = (4 * L) & 255;
    const int x2f2 = (4 * (3 + L)) & 255;
    const int x2ti = (4 * (6 + L)) & 255;

    // ---- state ----
    float h[33];
#pragma unroll
    for (int k = 0; k < 33; k++) h[k] = 0.f;
    float cc = 0.f;

    // per-lane P addresses: z float4 @ col 4*iG; L0 scalar @ col 128+clamp(L,4,57)
    const float* Pb = P + (size_t)b * TSTEPS * NPAD;
    int Lc = L; if (Lc < 4) Lc = 4; if (Lc > 57) Lc = 57;
    const float* pzp = Pb + 4 * iG;
    const float* plp = Pb + 128 + Lc;

    // step-0 seeds (carry = 0 -> pure precomp) and step-0 L0 precomp
    float4 z0 = *(const float4*)pzp;
    float zA = z0.x, zB = z0.y, zC = z0.z, zD = z0.w;
    float curl0 = *plp;
    // prefetch step-1
    float4 nz4 = *(const float4*)(pzp + NPAD);
    float nl0 = *(plp + NPAD);

    float* outp = out + (size_t)b * TSTEPS * 3 + L;

#pragma unroll 1
    for (int t = 0; t < TSTEPS; t++) {
        // issue loads for step t+2
        const int df = (t + 2 < TSTEPS) ? (t + 2) : (TSTEPS - 1);
        const float4 fz4 = *(const float4*)(pzp + (size_t)df * NPAD);
        const float fl0 = *(plp + (size_t)df * NPAD);

        // ---- Phase G: gate dots complete in zA..zD; all lane-local ----
        const float ia = actf(zA, -T2E, 0.f, 2.f, -1.f);
        const float ig = actf(zB, -L2E, 0.f, 1.f, 0.f);
        const float fg = actf(zC, -L2E, -L2E, 1.f, 0.f);   // sigmoid(z+1)
        const float og = actf(zD, -L2E, 0.f, 1.f, 0.f);
        cc = fmaf(cc, fg, ia * ig);
        const float hv = actf(cc, -T2E, 0.f, 2.f, -1.f) * og;

        // broadcast LSTM h, inter segment first (L0 is on the critical path)
#pragma unroll
        for (int k = 0; k < 18; k++) h[k] = rl(hv, k);

        // ---- Phase L0: 54 dots (len 18), 4-way split ----
        float A0 = curl0, A1 = 0.f, A2 = 0.f, A3 = 0.f;
#pragma unroll
        for (int k = 0; k < 16; k += 4) {
            A0 = fmaf(w0[k],     h[k],     A0);
            A1 = fmaf(w0[k + 1], h[k + 1], A1);
            A2 = fmaf(w0[k + 2], h[k + 2], A2);
            A3 = fmaf(w0[k + 3], h[k + 3], A3);
        }
        A0 = fmaf(w0[16], h[16], A0);
        A1 = fmaf(w0[17], h[17], A1);
        const float l0 = (A0 + A1) + (A2 + A3);

        // off-path: rest of hv broadcast + L1/L2 LSTM-h partial dots
#pragma unroll
        for (int k = 18; k < 33; k++) h[k] = rl(hv, k);
        float l1p = bias1;
#pragma unroll
        for (int k = 18; k < 30; k++) l1p = fmaf(w1[k], h[k], l1p);
        float l2p = bias2;
        l2p = fmaf(w2[12], h[30], l2p);
        l2p = fmaf(w2[13], h[31], l2p);
        l2p = fmaf(w2[14], h[32], l2p);

        // L0 combine
        {
            const float av = actf(l0, s0, 0.f, a0c, b0c);
            const float f1 = bperm(x0f1, av);
            const float f2 = bperm(x0f2, av);
            const float ti = bperm(x0ti, av);
            const float h0 = fmaf(ti, f2 - f1, f1);   // valid lanes 0..17
#pragma unroll
            for (int k = 0; k < 18; k++) h[k] = rl(h0, k);
        }

        // ---- seed next-step gates: inter segment (off path) ----
        zA = nz4.x; zB = nz4.y; zC = nz4.z; zD = nz4.w;
#pragma unroll
        for (int k = 0; k < 18; k++) {
            const float4 g4 = G4[k * 33 + iG];
            zA = fmaf(g4.x, h[k], zA);
            zB = fmaf(g4.y, h[k], zB);
            zC = fmaf(g4.z, h[k], zC);
            zD = fmaf(g4.w, h[k], zD);
        }

        // ---- Phase L1 residual: 18 terms over L0out, 4-way ----
        float B0 = l1p, B1 = 0.f, B2 = 0.f, B3 = 0.f;
#pragma unroll
        for (int k = 0; k < 16; k += 4) {
            B0 = fmaf(w1[k],     h[k],     B0);
            B1 = fmaf(w1[k + 1], h[k + 1], B1);
            B2 = fmaf(w1[k + 2], h[k + 2], B2);
            B3 = fmaf(w1[k + 3], h[k + 3], B3);
        }
        B0 = fmaf(w1[16], h[16], B0);
        B1 = fmaf(w1[17], h[17], B1);
        const float l1 = (B0 + B1) + (B2 + B3);
        {
            const float av = actf(l1, s1, 0.f, a1c, b1c);
            const float f1 = bperm(x1f1, av);
            const float f2 = bperm(x1f2, av);
            const float ti = bperm(x1ti, av);
            const float h1 = fmaf(ti, f2 - f1, f1);   // valid lanes 0..11
#pragma unroll
            for (int k = 0; k < 12; k++) h[18 + k] = rl(h1, k);
        }

        // ---- seed gates: command segment (off path) ----
#pragma unroll
        for (int k = 18; k < 30; k++) {
            const float4 g4 = G4[k * 33 + iG];
            zA = fmaf(g4.x, h[k], zA);
            zB = fmaf(g4.y, h[k], zB);
            zC = fmaf(g4.z, h[k], zC);
            zD = fmaf(g4.w, h[k], zD);
        }

        // ---- Phase L2 residual: 12 terms over L1out, 4-way ----
        float C0 = l2p, C1 = 0.f, C2 = 0.f, C3 = 0.f;
#pragma unroll
        for (int k = 0; k < 12; k += 4) {
            C0 = fmaf(w2[k],     h[18 + k],     C0);
            C1 = fmaf(w2[k + 1], h[18 + k + 1], C1);
            C2 = fmaf(w2[k + 2], h[18 + k + 2], C2);
            C3 = fmaf(w2[k + 3], h[18 + k + 3], C3);
        }
        const float l2 = (C0 + C1) + (C2 + C3);
        {
            const float av = actf(l2, s2, 0.f, a2c, b2c);
            const float f1 = bperm(x2f1, av);
            const float f2 = bperm(x2f2, av);
            const float ti = bperm(x2ti, av);
            const float h2 = fmaf(ti, f2 - f1, f1);   // valid lanes 0..2
            if (L < 3) outp[(size_t)t * 3] = h2;
            h[30] = rl(h2, 0); h[31] = rl(h2, 1); h[32] = rl(h2, 2);
        }

        // ---- seed gates: motor segment (trailing) ----
#pragma unroll
        for (int k = 30; k < 33; k++) {
            const float4 g4 = G4[k * 33 + iG];
            zA = fmaf(g4.x, h[k], zA);
            zB = fmaf(g4.y, h[k], zB);
            zC = fmaf(g4.z, h[k], zC);
            zD = fmaf(g4.w, h[k], zD);
        }

        // rotate prefetch pipeline
        curl0 = nl0;
        nz4 = fz4; nl0 = fl0;
    }
}

// ---------------------------------------------------------------------------
extern "C" void kernel_launch(void* const* d_in, const int* in_sizes, int n_in,
                              void* d_out, int out_size, void* d_ws, size_t ws_size,
                              hipStream_t stream) {
    const float* x       = (const float*)d_in[0];
    const float* fc1_w   = (const float*)d_in[1];
    const float* fc1_b   = (const float*)d_in[2];
    const float* lstm_wi = (const float*)d_in[3];
    const float* lstm_bi = (const float*)d_in[4];
    const float* lstm_wh = (const float*)d_in[5];
    const float* ff1w0 = (const float*)d_in[6];
    const float* ff2w0 = (const float*)d_in[7];
    const float* taw0  = (const float*)d_in[8];
    const float* tbw0  = (const float*)d_in[9];
    const float* ff1b0 = (const float*)d_in[10];
    const float* ff2b0 = (const float*)d_in[11];
    const float* tab0  = (const float*)d_in[12];
    const float* tbb0  = (const float*)d_in[13];
    const float* ff1w1 = (const float*)d_in[14];
    const float* ff2w1 = (const float*)d_in[15];
    const float* taw1  = (const float*)d_in[16];
    const float* tbw1  = (const float*)d_in[17];
    const float* ff1b1 = (const float*)d_in[18];
    const float* ff2b1 = (const float*)d_in[19];
    const float* tab1  = (const float*)d_in[20];
    const float* tbb1  = (const float*)d_in[21];
    const float* ff1w2 = (const float*)d_in[22];
    const float* ff2w2 = (const float*)d_in[23];
    const float* taw2  = (const float*)d_in[24];
    const float* tbw2  = (const float*)d_in[25];
    const float* ff1b2 = (const float*)d_in[26];
    const float* ff2b2 = (const float*)d_in[27];
    const float* tab2  = (const float*)d_in[28];
    const float* tbb2  = (const float*)d_in[29];
    const float* mask0 = (const float*)d_in[30];
    const float* mask1 = (const float*)d_in[31];
    const float* mask2 = (const float*)d_in[32];

    float* Wc = (float*)d_ws;            // 512*192 floats
    float* bc = Wc + 512 * NW;           // 192 floats
    float* P  = bc + NW;                 // 32768*192 floats (~25.2 MB)
    float* outp = (float*)d_out;

    fold_kernel<<<192, 256, 0, stream>>>(fc1_w, fc1_b, lstm_wi, lstm_bi,
                                         ff1w0, ff2w0, taw0, tbw0,
                                         ff1b0, ff2b0, tab0, tbb0, mask0, Wc, bc);
    gemm_kernel<<<dim3(BT / 128, 3), 128, 0, stream>>>(x, Wc, bc, P);
    scan_kernel<<<NBATCH, 64, 0, stream>>>(P, lstm_wh,
                                           ff1w0, ff2w0, taw0, tbw0,
                                           ff1w1, ff2w1, taw1, tbw1,
                                           ff1b1, ff2b1, tab1, tbb1,
                                           ff1w2, ff2w2, taw2, tbw2,
                                           ff1b2, ff2b2, tab2, tbb2,
                                           mask1, mask2, outp);
}

// Round 11
// 604.774 us; speedup vs baseline: 1.0258x; 1.0258x over previous
//
#include <hip/hip_runtime.h>
#include <hip/hip_bf16.h>

// Problem constants
#define BT 32768      // B*T = 64*512
#define TSTEPS 512
#define NBATCH 64
#define KDIM 512      // IN_DIM
#define NPAD 192      // P row stride
#define NW 192        // Wc cols

#define L2E 1.4426950408889634f
#define T2E 2.8853900817779268f

__device__ __forceinline__ float rl(float v, int lane) {
    return __int_as_float(__builtin_amdgcn_readlane(__float_as_int(v), lane));
}
__device__ __forceinline__ float bperm(int byteidx, float v) {
    return __int_as_float(__builtin_amdgcn_ds_bpermute(byteidx, __float_as_int(v)));
}
// unified activation: a * rcp(1 + exp2(s*x + sc)) + b
__device__ __forceinline__ float actf(float x, float s, float sc, float a, float b) {
    float e = exp2f(fmaf(s, x, sc));
    return fmaf(a, __builtin_amdgcn_rcpf(1.f + e), b);
}

// P column layout (scan-friendly):
//   z dot (gate g, neuron i) -> col 4*i+g   (cols 0..131; lane i reads float4 @ 4i)
//   L0 dot e -> col 132+e                   (cols 132..185; lane 4+e reads scalar)
//   cols 186..191 pad (zero)
__device__ __forceinline__ int permpos(int o) {
    if (o < 132) { int g = o / 33, i = o - g * 33; return 4 * i + g; }
    return o;
}

// ---------------------------------------------------------------------------
// Kernel 1: fold fc1 into the stacked scan-input projection (permuted cols).
// ---------------------------------------------------------------------------
__global__ __launch_bounds__(256) void fold_kernel(
    const float* __restrict__ fc1_w, const float* __restrict__ fc1_b,
    const float* __restrict__ lstm_wi, const float* __restrict__ lstm_bi,
    const float* __restrict__ ff1w0, const float* __restrict__ ff2w0,
    const float* __restrict__ taw0, const float* __restrict__ tbw0,
    const float* __restrict__ ff1b0, const float* __restrict__ ff2b0,
    const float* __restrict__ tab0, const float* __restrict__ tbb0,
    const float* __restrict__ mask0,
    float* __restrict__ Wc, float* __restrict__ bc)
{
    const int o = blockIdx.x;   // 0..191 logical column
    const int t = threadIdx.x;  // 0..255 = latent index l
    const int p = permpos(o);
    __shared__ float wrow[256];
    __shared__ float red[256];

    float wl = 0.f, b0 = 0.f;
    if (o < 132) { wl = lstm_wi[o * 256 + t]; b0 = lstm_bi[o]; }
    else if (o < 186) {
        const int e = o - 132, m = e / 18, i = e - m * 18;
        if (m == 0)      { wl = ff1w0[i * 274 + t] * mask0[i * 274 + t]; b0 = ff1b0[i]; }
        else if (m == 1) { wl = ff2w0[i * 274 + t] * mask0[i * 274 + t]; b0 = ff2b0[i]; }
        else             { wl = taw0[i * 274 + t] + tbw0[i * 274 + t];   b0 = tab0[i] + tbb0[i]; }
    }
    wrow[t] = wl;
    __syncthreads();

    float acc0 = 0.f, acc1 = 0.f;
    for (int l = 0; l < 256; l++) {
        float w = wrow[l];
        acc0 = fmaf(fc1_w[l * 512 + t], w, acc0);
        acc1 = fmaf(fc1_w[l * 512 + t + 256], w, acc1);
    }
    Wc[(size_t)t * NW + p] = acc0;
    Wc[(size_t)(t + 256) * NW + p] = acc1;

    red[t] = fc1_b[t] * wl;
    __syncthreads();
    for (int s = 128; s > 0; s >>= 1) {
        if (t < s) red[t] += red[t + s];
        __syncthreads();
    }
    if (t == 0) bc[p] = red[0] + b0;
}

// ---------------------------------------------------------------------------
// Kernel 2: P[m][n] = sum_k X[m][k]*Wc[k][n] + bc[n], fp32 LDS-tiled GEMM.
// M=32768, K=512, N=192. Tile 128x64x16, 256 threads, 8x4 acc/thread with
// the 8 m-rows as TWO quads 64 apart (j, 64+j): As b128 reads are then
// exactly 2-way bank-aliased (free per m136) instead of R9/R10's 4-way.
// Bs reads are 4-address wave broadcasts (conflict-free, row padded to 68).
// Register double-buffer on the global loads: vmcnt wait lands after the
// ~2000-cyc compute of the previous tile, not between the barriers.
// Grid (256,3) = 768 blocks = 3 blocks/CU = 12 waves/CU.
// ---------------------------------------------------------------------------
__global__ __launch_bounds__(256) void gemm_kernel(
    const float* __restrict__ X, const float* __restrict__ Wc,
    const float* __restrict__ bc, float* __restrict__ P)
{
    __shared__ float As[16][128];   // [k][m]
    __shared__ float Bs[16][68];    // [k][n], padded
    const int tid = threadIdx.x;    // 0..255
    const int m0 = blockIdx.x * 128;
    const int n0 = blockIdx.y * 64;
    // A loader: row lr = tid>>1 (0..127), k-cols lc..lc+7 (lc = 0 or 8)
    const int lr = tid >> 1;
    const int lc = (tid & 1) << 3;
    // B loader: bk = tid>>4 (0..15), bn = (tid&15)*4 (0..60), 1 float4/thread
    const int bk = tid >> 4;
    const int bn = (tid & 15) << 2;
    // compute map: m-quads {j4, 64+j4}, n-quad c4
    const int j4 = (tid & 15) << 2;   // 0..60
    const int c4 = (tid >> 4) << 2;   // 0..60

    float acc0[4][4], acc1[4][4];
#pragma unroll
    for (int i = 0; i < 4; i++)
#pragma unroll
        for (int j = 0; j < 4; j++) { acc0[i][j] = 0.f; acc1[i][j] = 0.f; }

    const float* xp = X + (size_t)(m0 + lr) * KDIM + lc;
    const float* wp = Wc + (size_t)bk * NW + n0 + bn;

    // preload tile 0 into registers
    float4 a0 = *(const float4*)(xp);
    float4 a1 = *(const float4*)(xp + 4);
    float4 bv = *(const float4*)(wp);

    for (int k0 = 0; k0 < KDIM; k0 += 16) {
        __syncthreads();
        As[lc + 0][lr] = a0.x; As[lc + 1][lr] = a0.y;
        As[lc + 2][lr] = a0.z; As[lc + 3][lr] = a0.w;
        As[lc + 4][lr] = a1.x; As[lc + 5][lr] = a1.y;
        As[lc + 6][lr] = a1.z; As[lc + 7][lr] = a1.w;
        *(float4*)&Bs[bk][bn] = bv;
        __syncthreads();
        if (k0 + 16 < KDIM) {
            a0 = *(const float4*)(xp + k0 + 16);
            a1 = *(const float4*)(xp + k0 + 20);
            bv = *(const float4*)(wp + (size_t)(k0 + 16) * NW);
        }
#pragma unroll
        for (int k = 0; k < 16; k++) {
            const float4 xa = *(const float4*)&As[k][j4];
            const float4 xb = *(const float4*)&As[k][64 + j4];
            const float4 bq = *(const float4*)&Bs[k][c4];
            acc0[0][0] = fmaf(xa.x, bq.x, acc0[0][0]); acc0[0][1] = fmaf(xa.x, bq.y, acc0[0][1]);
            acc0[0][2] = fmaf(xa.x, bq.z, acc0[0][2]); acc0[0][3] = fmaf(xa.x, bq.w, acc0[0][3]);
            acc0[1][0] = fmaf(xa.y, bq.x, acc0[1][0]); acc0[1][1] = fmaf(xa.y, bq.y, acc0[1][1]);
            acc0[1][2] = fmaf(xa.y, bq.z, acc0[1][2]); acc0[1][3] = fmaf(xa.y, bq.w, acc0[1][3]);
            acc0[2][0] = fmaf(xa.z, bq.x, acc0[2][0]); acc0[2][1] = fmaf(xa.z, bq.y, acc0[2][1]);
            acc0[2][2] = fmaf(xa.z, bq.z, acc0[2][2]); acc0[2][3] = fmaf(xa.z, bq.w, acc0[2][3]);
            acc0[3][0] = fmaf(xa.w, bq.x, acc0[3][0]); acc0[3][1] = fmaf(xa.w, bq.y, acc0[3][1]);
            acc0[3][2] = fmaf(xa.w, bq.z, acc0[3][2]); acc0[3][3] = fmaf(xa.w, bq.w, acc0[3][3]);
            acc1[0][0] = fmaf(xb.x, bq.x, acc1[0][0]); acc1[0][1] = fmaf(xb.x, bq.y, acc1[0][1]);
            acc1[0][2] = fmaf(xb.x, bq.z, acc1[0][2]); acc1[0][3] = fmaf(xb.x, bq.w, acc1[0][3]);
            acc1[1][0] = fmaf(xb.y, bq.x, acc1[1][0]); acc1[1][1] = fmaf(xb.y, bq.y, acc1[1][1]);
            acc1[1][2] = fmaf(xb.y, bq.z, acc1[1][2]); acc1[1][3] = fmaf(xb.y, bq.w, acc1[1][3]);
            acc1[2][0] = fmaf(xb.z, bq.x, acc1[2][0]); acc1[2][1] = fmaf(xb.z, bq.y, acc1[2][1]);
            acc1[2][2] = fmaf(xb.z, bq.z, acc1[2][2]); acc1[2][3] = fmaf(xb.z, bq.w, acc1[2][3]);
            acc1[3][0] = fmaf(xb.w, bq.x, acc1[3][0]); acc1[3][1] = fmaf(xb.w, bq.y, acc1[3][1]);
            acc1[3][2] = fmaf(xb.w, bq.z, acc1[3][2]); acc1[3][3] = fmaf(xb.w, bq.w, acc1[3][3]);
        }
    }

    {
        const float4 bias = *(const float4*)(bc + n0 + c4);
#pragma unroll
        for (int i = 0; i < 4; i++) {
            float4 r;
            r.x = acc0[i][0] + bias.x; r.y = acc0[i][1] + bias.y;
            r.z = acc0[i][2] + bias.z; r.w = acc0[i][3] + bias.w;
            *(float4*)(P + (size_t)(m0 + j4 + i) * NPAD + n0 + c4) = r;
            float4 s;
            s.x = acc1[i][0] + bias.x; s.y = acc1[i][1] + bias.y;
            s.z = acc1[i][2] + bias.z; s.w = acc1[i][3] + bias.w;
            *(float4*)(P + (size_t)(m0 + 64 + j4 + i) * NPAD + n0 + c4) = s;
        }
    }
}

// ---------------------------------------------------------------------------
// Kernel 3: persistent scan, one wave per batch element.  (unchanged from R8)
// ---------------------------------------------------------------------------
__global__ __launch_bounds__(64)
__attribute__((amdgpu_waves_per_eu(1, 1)))
void scan_kernel(
    const float* __restrict__ P, const float* __restrict__ lstm_wh,
    const float* __restrict__ ff1w0, const float* __restrict__ ff2w0,
    const float* __restrict__ taw0, const float* __restrict__ tbw0,
    const float* __restrict__ ff1w1, const float* __restrict__ ff2w1,
    const float* __restrict__ taw1, const float* __restrict__ tbw1,
    const float* __restrict__ ff1b1, const float* __restrict__ ff2b1,
    const float* __restrict__ tab1, const float* __restrict__ tbb1,
    const float* __restrict__ ff1w2, const float* __restrict__ ff2w2,
    const float* __restrict__ taw2, const float* __restrict__ tbw2,
    const float* __restrict__ ff1b2, const float* __restrict__ ff2b2,
    const float* __restrict__ tab2, const float* __restrict__ tbb2,
    const float* __restrict__ mask1, const float* __restrict__ mask2,
    float* __restrict__ out)
{
    const int L = threadIdx.x;
    const int b = blockIdx.x;

    // packed gate weights: G4[k*33+i] = (w_ia, w_ig, w_fg, w_og) for neuron i, term k
    __shared__ float4 G4[33 * 33];
    for (int idx = L; idx < 33 * 33; idx += 64) {
        const int k = idx / 33, i = idx - k * 33;
        float4 g;
        g.x = lstm_wh[i * 33 + k];
        g.y = lstm_wh[(33 + i) * 33 + k];
        g.z = lstm_wh[(66 + i) * 33 + k];
        g.w = lstm_wh[(99 + i) * 33 + k];
        G4[idx] = g;
    }
    __syncthreads();

    const int iG = (L < 33) ? L : 32;   // gate neuron (lanes 33..63 duplicate 32)

    // ---- L0 weights: dot e=L-4 (clamped), m=e/18; ta+tb merged ----
    float w0[18];
    {
        int e = L - 4; e = (e < 0) ? 0 : ((e > 53) ? 53 : e);
        const int m = e / 18, i = e - m * 18;
        const float* pa = (m == 0) ? ff1w0 : (m == 1) ? ff2w0 : taw0;
#pragma unroll
        for (int k = 0; k < 18; k++) {
            float w = pa[i * 274 + 256 + k];
            if (m == 2) w += tbw0[i * 274 + 256 + k];
            w0[k] = w;
        }
    }
    // ---- L1 weights: dot d=m*12+i on lanes 0..35 ----
    float w1[30], bias1;
    {
        const int d = (L < 36) ? L : 35;
        const int m = d / 12, i = d - m * 12;
        const float* pa = (m == 0) ? ff1w1 : (m == 1) ? ff2w1 : taw1;
#pragma unroll
        for (int k = 0; k < 30; k++) {
            float w = pa[i * 30 + k];
            if (m == 2) w += tbw1[i * 30 + k];
            else w *= mask1[i * 30 + k];
            w1[k] = w;
        }
        bias1 = (m == 0) ? ff1b1[i] : (m == 1) ? ff2b1[i] : (tab1[i] + tbb1[i]);
    }
    // ---- L2 weights: dot d=m*3+i on lanes 0..8 ----
    float w2[15], bias2;
    {
        const int d = (L < 9) ? L : 8;
        const int m = d / 3, i = d - m * 3;
        const float* pa = (m == 0) ? ff1w2 : (m == 1) ? ff2w2 : taw2;
#pragma unroll
        for (int k = 0; k < 15; k++) {
            float w = pa[i * 15 + k];
            if (m == 2) w += tbw2[i * 15 + k];
            else w *= mask2[i * 15 + k];
            w2[k] = w;
        }
        bias2 = (m == 0) ? ff1b2[i] : (m == 1) ? ff2b2[i] : (tab2[i] + tbb2[i]);
    }

    // ---- per-lane activation constants (layers only) ----
    const float s0  = (L < 40) ? -T2E : -L2E;   // L0: lanes 4..39 tanh, 40..57 sig
    const float a0c = (L < 40) ? 2.f : 1.f;
    const float b0c = (L < 40) ? -1.f : 0.f;
    const float s1  = (L < 24) ? -T2E : -L2E;
    const float a1c = (L < 24) ? 2.f : 1.f;
    const float b1c = (L < 24) ? -1.f : 0.f;
    const float s2  = (L < 6) ? -T2E : -L2E;
    const float a2c = (L < 6) ? 2.f : 1.f;
    const float b2c = (L < 6) ? -1.f : 0.f;

    // ---- per-lane bpermute byte indices (layer combines) ----
    const int x0f1 = (4 * (4 + L)) & 255;
    const int x0f2 = (4 * (22 + L)) & 255;
    const int x0ti = (4 * (40 + L)) & 255;
    const int x1f1 = (4 * L) & 255;
    const int x1f2 = (4 * (12 + L)) & 255;
    const int x1ti = (4 * (24 + L)) & 255;
    const int x2f1 = (4 * L) & 255;
    const int x2f2 = (4 * (3 + L)) & 255;
    const int x2ti = (4 * (6 + L)) & 255;

    // ---- state ----
    float h[33];
#pragma unroll
    for (int k = 0; k < 33; k++) h[k] = 0.f;
    float cc = 0.f;

    // per-lane P addresses: z float4 @ col 4*iG; L0 scalar @ col 128+clamp(L,4,57)
    const float* Pb = P + (size_t)b * TSTEPS * NPAD;
    int Lc = L; if (Lc < 4) Lc = 4; if (Lc > 57) Lc = 57;
    const float* pzp = Pb + 4 * iG;
    const float* plp = Pb + 128 + Lc;

    // step-0 seeds (carry = 0 -> pure precomp) and step-0 L0 precomp
    float4 z0 = *(const float4*)pzp;
    float zA = z0.x, zB = z0.y, zC = z0.z, zD = z0.w;
    float curl0 = *plp;
    // prefetch step-1
    float4 nz4 = *(const float4*)(pzp + NPAD);
    float nl0 = *(plp + NPAD);

    float* outp = out + (size_t)b * TSTEPS * 3 + L;

#pragma unroll 1
    for (int t = 0; t < TSTEPS; t++) {
        // issue loads for step t+2
        const int df = (t + 2 < TSTEPS) ? (t + 2) : (TSTEPS - 1);
        const float4 fz4 = *(const float4*)(pzp + (size_t)df * NPAD);
        const float fl0 = *(plp + (size_t)df * NPAD);

        // ---- Phase G: gate dots complete in zA..zD; all lane-local ----
        const float ia = actf(zA, -T2E, 0.f, 2.f, -1.f);
        const float ig = actf(zB, -L2E, 0.f, 1.f, 0.f);
        const float fg = actf(zC, -L2E, -L2E, 1.f, 0.f);   // sigmoid(z+1)
        const float og = actf(zD, -L2E, 0.f, 1.f, 0.f);
        cc = fmaf(cc, fg, ia * ig);
        const float hv = actf(cc, -T2E, 0.f, 2.f, -1.f) * og;

        // broadcast LSTM h, inter segment first (L0 is on the critical path)
#pragma unroll
        for (int k = 0; k < 18; k++) h[k] = rl(hv, k);

        // ---- Phase L0: 54 dots (len 18), 4-way split ----
        float A0 = curl0, A1 = 0.f, A2 = 0.f, A3 = 0.f;
#pragma unroll
        for (int k = 0; k < 16; k += 4) {
            A0 = fmaf(w0[k],     h[k],     A0);
            A1 = fmaf(w0[k + 1], h[k + 1], A1);
            A2 = fmaf(w0[k + 2], h[k + 2], A2);
            A3 = fmaf(w0[k + 3], h[k + 3], A3);
        }
        A0 = fmaf(w0[16], h[16], A0);
        A1 = fmaf(w0[17], h[17], A1);
        const float l0 = (A0 + A1) + (A2 + A3);

        // off-path: rest of hv broadcast + L1/L2 LSTM-h partial dots
#pragma unroll
        for (int k = 18; k < 33; k++) h[k] = rl(hv, k);
        float l1p = bias1;
#pragma unroll
        for (int k = 18; k < 30; k++) l1p = fmaf(w1[k], h[k], l1p);
        float l2p = bias2;
        l2p = fmaf(w2[12], h[30], l2p);
        l2p = fmaf(w2[13], h[31], l2p);
        l2p = fmaf(w2[14], h[32], l2p);

        // L0 combine
        {
            const float av = actf(l0, s0, 0.f, a0c, b0c);
            const float f1 = bperm(x0f1, av);
            const float f2 = bperm(x0f2, av);
            const float ti = bperm(x0ti, av);
            const float h0 = fmaf(ti, f2 - f1, f1);   // valid lanes 0..17
#pragma unroll
            for (int k = 0; k < 18; k++) h[k] = rl(h0, k);
        }

        // ---- seed next-step gates: inter segment (off path) ----
        zA = nz4.x; zB = nz4.y; zC = nz4.z; zD = nz4.w;
#pragma unroll
        for (int k = 0; k < 18; k++) {
            const float4 g4 = G4[k * 33 + iG];
            zA = fmaf(g4.x, h[k], zA);
            zB = fmaf(g4.y, h[k], zB);
            zC = fmaf(g4.z, h[k], zC);
            zD = fmaf(g4.w, h[k], zD);
        }

        // ---- Phase L1 residual: 18 terms over L0out, 4-way ----
        float B0 = l1p, B1 = 0.f, B2 = 0.f, B3 = 0.f;
#pragma unroll
        for (int k = 0; k < 16; k += 4) {
            B0 = fmaf(w1[k],     h[k],     B0);
            B1 = fmaf(w1[k + 1], h[k + 1], B1);
            B2 = fmaf(w1[k + 2], h[k + 2], B2);
            B3 = fmaf(w1[k + 3], h[k + 3], B3);
        }
        B0 = fmaf(w1[16], h[16], B0);
        B1 = fmaf(w1[17], h[17], B1);
        const float l1 = (B0 + B1) + (B2 + B3);
        {
            const float av = actf(l1, s1, 0.f, a1c, b1c);
            const float f1 = bperm(x1f1, av);
            const float f2 = bperm(x1f2, av);
            const float ti = bperm(x1ti, av);
            const float h1 = fmaf(ti, f2 - f1, f1);   // valid lanes 0..11
#pragma unroll
            for (int k = 0; k < 12; k++) h[18 + k] = rl(h1, k);
        }

        // ---- seed gates: command segment (off path) ----
#pragma unroll
        for (int k = 18; k < 30; k++) {
            const float4 g4 = G4[k * 33 + iG];
            zA = fmaf(g4.x, h[k], zA);
            zB = fmaf(g4.y, h[k], zB);
            zC = fmaf(g4.z, h[k], zC);
            zD = fmaf(g4.w, h[k], zD);
        }

        // ---- Phase L2 residual: 12 terms over L1out, 4-way ----
        float C0 = l2p, C1 = 0.f, C2 = 0.f, C3 = 0.f;
#pragma unroll
        for (int k = 0; k < 12; k += 4) {
            C0 = fmaf(w2[k],     h[18 + k],     C0);
            C1 = fmaf(w2[k + 1], h[18 + k + 1], C1);
            C2 = fmaf(w2[k + 2], h[18 + k + 2], C2);
            C3 = fmaf(w2[k + 3], h[18 + k + 3], C3);
        }
        const float l2 = (C0 + C1) + (C2 + C3);
        {
            const float av = actf(l2, s2, 0.f, a2c, b2c);
            const float f1 = bperm(x2f1, av);
            const float f2 = bperm(x2f2, av);
            const float ti = bperm(x2ti, av);
            const float h2 = fmaf(ti, f2 - f1, f1);   // valid lanes 0..2
            if (L < 3) outp[(size_t)t * 3] = h2;
            h[30] = rl(h2, 0); h[31] = rl(h2, 1); h[32] = rl(h2, 2);
        }

        // ---- seed gates: motor segment (trailing) ----
#pragma unroll
        for (int k = 30; k < 33; k++) {
            const float4 g4 = G4[k * 33 + iG];
            zA = fmaf(g4.x, h[k], zA);
            zB = fmaf(g4.y, h[k], zB);
            zC = fmaf(g4.z, h[k], zC);
            zD = fmaf(g4.w, h[k], zD);
        }

        // rotate prefetch pipeline
        curl0 = nl0;
        nz4 = fz4; nl0 = fl0;
    }
}

// ---------------------------------------------------------------------------
extern "C" void kernel_launch(void* const* d_in, const int* in_sizes, int n_in,
                              void* d_out, int out_size, void* d_ws, size_t ws_size,
                              hipStream_t stream) {
    const float* x       = (const float*)d_in[0];
    const float* fc1_w   = (const float*)d_in[1];
    const float* fc1_b   = (const float*)d_in[2];
    const float* lstm_wi = (const float*)d_in[3];
    const float* lstm_bi = (const float*)d_in[4];
    const float* lstm_wh = (const float*)d_in[5];
    const float* ff1w0 = (const float*)d_in[6];
    const float* ff2w0 = (const float*)d_in[7];
    const float* taw0  = (const float*)d_in[8];
    const float* tbw0  = (const float*)d_in[9];
    const float* ff1b0 = (const float*)d_in[10];
    const float* ff2b0 = (const float*)d_in[11];
    const float* tab0  = (const float*)d_in[12];
    const float* tbb0  = (const float*)d_in[13];
    const float* ff1w1 = (const float*)d_in[14];
    const float* ff2w1 = (const float*)d_in[15];
    const float* taw1  = (const float*)d_in[16];
    const float* tbw1  = (const float*)d_in[17];
    const float* ff1b1 = (const float*)d_in[18];
    const float* ff2b1 = (const float*)d_in[19];
    const float* tab1  = (const float*)d_in[20];
    const float* tbb1  = (const float*)d_in[21];
    const float* ff1w2 = (const float*)d_in[22];
    const float* ff2w2 = (const float*)d_in[23];
    const float* taw2  = (const float*)d_in[24];
    const float* tbw2  = (const float*)d_in[25];
    const float* ff1b2 = (const float*)d_in[26];
    const float* ff2b2 = (const float*)d_in[27];
    const float* tab2  = (const float*)d_in[28];
    const float* tbb2  = (const float*)d_in[29];
    const float* mask0 = (const float*)d_in[30];
    const float* mask1 = (const float*)d_in[31];
    const float* mask2 = (const float*)d_in[32];

    float* Wc = (float*)d_ws;            // 512*192 floats
    float* bc = Wc + 512 * NW;           // 192 floats
    float* P  = bc + NW;                 // 32768*192 floats (~25.2 MB)
    float* outp = (float*)d_out;

    fold_kernel<<<192, 256, 0, stream>>>(fc1_w, fc1_b, lstm_wi, lstm_bi,
                                         ff1w0, ff2w0, taw0, tbw0,
                                         ff1b0, ff2b0, tab0, tbb0, mask0, Wc, bc);
    gemm_kernel<<<dim3(BT / 128, 3), 256, 0, stream>>>(x, Wc, bc, P);
    scan_kernel<<<NBATCH, 64, 0, stream>>>(P, lstm_wh,
                                           ff1w0, ff2w0, taw0, tbw0,
                                           ff1w1, ff2w1, taw1, tbw1,
                                           ff1b1, ff2b1, tab1, tbb1,
                                           ff1w2, ff2w2, taw2, tbw2,
                                           ff1b2, ff2b2, tab2, tbb2,
                                           mask1, mask2, outp);
}